// Round 16
// baseline (83.307 us; speedup 1.0000x reference)
//
#include <hip/hip_runtime.h>
#include <hip/hip_bf16.h>
#include <math.h>

#define NV 50257
#define NE 256
#define NC 48
#define NB 64
#define NT 1024
#define NCHUNK 32          // 31 chunks x 32 factors + 1 chunk x 31 = 1023
#define ELD 68             // scan El row stride (floats)
#define L2E 1.44269504088896340736f
#define LN2 0.69314718055994530942f

typedef __attribute__((ext_vector_type(8)))  short bf16x8;
typedef __attribute__((ext_vector_type(16))) float f32x16;

__device__ __forceinline__ unsigned pk_bf16(float lo, float hi) {
    unsigned r;
    asm("v_cvt_pk_bf16_f32 %0, %1, %2" : "=v"(r) : "v"(lo), "v"(hi));
    return r;
}
__device__ __forceinline__ bf16x8 mk8(unsigned u0, unsigned u1, unsigned u2, unsigned u3) {
    union { unsigned u[4]; bf16x8 v; } t;
    t.u[0] = u0; t.u[1] = u1; t.u[2] = u2; t.u[3] = u3;
    return t.v;
}

// ---------------------------------------------------------------------------
// Kernel 0: prep — W bf16 MFMA fragments (layout identical to r11's Wf,
// verified). 256 threads, no exp2 -> fast. Also zeroes out_scalar.
//   Wfrag[kf*128 + rt*64 + lane]
// ---------------------------------------------------------------------------
__global__ __launch_bounds__(256) void prep_kernel(
    const float* __restrict__ w, uint4* __restrict__ Wfrag,
    float* __restrict__ out_scalar)
{
    const int tid = threadIdx.x;
    if (tid == 0) *out_scalar = 0.f;
#pragma unroll
    for (int i = 0; i < 8; ++i) {
        const int f = i * 256 + tid;
        const int lane_ = f & 63;
        const int rt_ = (f >> 6) & 1;
        const int kf_ = f >> 7;
        const int r = (lane_ & 31) + 32 * rt_;
        const int h_ = lane_ >> 5;
        uint4 u = make_uint4(0u, 0u, 0u, 0u);
        if (r < NC) {
            const float* wr = w + r * NE + 16 * kf_ + 4 * h_;
            float4 w0 = *(const float4*)(wr);
            float4 w1 = *(const float4*)(wr + 8);
            u.x = pk_bf16(w0.x, w0.y); u.y = pk_bf16(w0.z, w0.w);
            u.z = pk_bf16(w1.x, w1.y); u.w = pk_bf16(w1.z, w1.w);
        }
        Wfrag[f] = u;
    }
}

// ---------------------------------------------------------------------------
// Kernel 1 (FUSED): per block (chunk j, batch b):
//   prologue: compute logits for 64 token slots via MFMA (wave0: t0+1..t0+32
//   -> E rows + out + emit partials; wave1: t0-31..t0 clamped -> out dups),
//   then the r10/r12 K=48 matrix-scan loop.
// ---------------------------------------------------------------------------
__device__ __forceinline__ bf16x8 mkA(const float* __restrict__ trans, int r, int h, int kf) {
    unsigned u[4];
#pragma unroll
    for (int p = 0; p < 4; ++p) {
        const int i0 = 2 * p;
        const int k0 = 16 * kf + 4 * h + (i0 & 3) + 8 * (i0 >> 2);
        const int k1 = k0 + 1;
        float v0 = (r < NC && k0 < NC) ? exp2f(trans[k0 * NC + r] * L2E) : 0.f;
        float v1 = (r < NC && k1 < NC) ? exp2f(trans[k1 * NC + r] * L2E) : 0.f;
        u[p] = pk_bf16(v0, v1);
    }
    return mk8(u[0], u[1], u[2], u[3]);
}

__device__ __forceinline__ f32x16 mkW(const float* __restrict__ trans, int rt, int ct, int h, int l31) {
    f32x16 r;
#pragma unroll
    for (int reg = 0; reg < 16; ++reg) {
        const int rw = 32 * rt + (reg & 3) + 8 * (reg >> 2) + 4 * h;
        const int cc = 32 * ct + l31;
        r[reg] = (rw < NC && cc < NC) ? exp2f(trans[cc * NC + rw] * L2E) : 0.f;
    }
    return r;
}

__device__ __forceinline__ f32x16 mm3(bf16x8 a0, bf16x8 a1, bf16x8 a2,
                                      bf16x8 b0, bf16x8 b1, bf16x8 b2) {
    f32x16 z;
#pragma unroll
    for (int i = 0; i < 16; ++i) z[i] = 0.f;
    f32x16 d = __builtin_amdgcn_mfma_f32_32x32x16_bf16(a0, b0, z, 0, 0, 0);
    d = __builtin_amdgcn_mfma_f32_32x32x16_bf16(a1, b1, d, 0, 0, 0);
    d = __builtin_amdgcn_mfma_f32_32x32x16_bf16(a2, b2, d, 0, 0, 0);
    return d;
}

__device__ __forceinline__ void scaleRows(f32x16& A, const float* ef, int rt, int h) {
#pragma unroll
    for (int g = 0; g < 4; ++g) {
        float4 e = *(const float4*)(ef + 32 * rt + 8 * g + 4 * h);
        A[4*g+0] *= e.x; A[4*g+1] *= e.y; A[4*g+2] *= e.z; A[4*g+3] *= e.w;
    }
}

__device__ __forceinline__ void storeQ(unsigned* __restrict__ cbase, const f32x16& A,
                                       float inv, int rt, int ct, int h, int l31) {
#pragma unroll
    for (int g = 0; g < 4; ++g)
#pragma unroll
        for (int pp = 0; pp < 2; ++pp) {
            const int reg = 4 * g + 2 * pp;
            unsigned u = pk_bf16(A[reg] * inv, A[reg + 1] * inv);
            const int rw = 32 * rt + 2 * pp + 8 * g + 4 * h;
            cbase[(rw >> 1) * 64 + 32 * ct + l31] = u;
        }
}

#define MKB1(BD, S, q, eo)                                                \
  {                                                                       \
    float4 _e0 = *(const float4*)(ep + (eo));                             \
    float4 _e1 = *(const float4*)(ep + (eo) + 8);                         \
    unsigned _u0 = pk_bf16(S[(q)+0]*_e0.x, S[(q)+1]*_e0.y);               \
    unsigned _u1 = pk_bf16(S[(q)+2]*_e0.z, S[(q)+3]*_e0.w);               \
    unsigned _u2 = pk_bf16(S[(q)+4]*_e1.x, S[(q)+5]*_e1.y);               \
    unsigned _u3 = pk_bf16(S[(q)+6]*_e1.z, S[(q)+7]*_e1.w);               \
    BD = mk8(_u0, _u1, _u2, _u3);                                         \
  }

__global__ __launch_bounds__(128, 3) void scan_kernel(
    const float* __restrict__ trans, const int* __restrict__ x,
    const int* __restrict__ labels, const float* __restrict__ emb,
    const float* __restrict__ bias, const uint4* __restrict__ Wfrag,
    float* __restrict__ out, float* __restrict__ nsum_part,
    unsigned* __restrict__ Cpk, float* __restrict__ S2tab)
{
    const int j = blockIdx.x;          // chunk
    const int b = blockIdx.y;          // batch
    const int tid = threadIdx.x;
    const int ct = tid >> 6;           // wave
    const int lane = tid & 63;
    const int h = lane >> 5, l31 = lane & 31;
    const int t0 = j * 32;
    const int cl = (j == NCHUNK - 1) ? 31 : 32;

    __shared__ __align__(16) float El[32 * ELD];
    __shared__ float mxs[2], svs_sh;

    // ================= PROLOGUE: fused logits =================
    // wave0: tokens t0+1+l31 ; wave1: tokens t0-31+l31 (clamped in-batch)
    const int tok_raw = (ct == 0) ? (t0 + 1 + l31) : (t0 - 31 + l31);
    const int tokc = min(max(tok_raw, 0), NT - 1);
    const float* __restrict__ erow = emb + (size_t)x[b * NT + tokc] * NE + 4 * h;

    float4 bb[6];
#pragma unroll
    for (int g = 0; g < 4; ++g) bb[g] = *(const float4*)(bias + 8 * g + 4 * h);
#pragma unroll
    for (int g = 0; g < 2; ++g) bb[4 + g] = *(const float4*)(bias + 32 + 8 * g + 4 * h);

    f32x16 acc0, acc1;
#pragma unroll
    for (int i = 0; i < 16; ++i) { acc0[i] = 0.f; acc1[i] = 0.f; }

    // software-pipelined K loop (16 kf): A from Wfrag (L2, coalesced),
    // B from own emb row (L3)
    uint4 a0c = Wfrag[lane], a1c = Wfrag[64 + lane];
    float4 e0c = *(const float4*)(erow);
    float4 e1c = *(const float4*)(erow + 8);
#pragma unroll
    for (int kf = 0; kf < 16; ++kf) {
        uint4 a0n, a1n; float4 e0n, e1n;
        if (kf < 15) {
            a0n = Wfrag[(kf + 1) * 128 + lane];
            a1n = Wfrag[(kf + 1) * 128 + 64 + lane];
            e0n = *(const float4*)(erow + 16 * (kf + 1));
            e1n = *(const float4*)(erow + 16 * (kf + 1) + 8);
        }
        bf16x8 B = mk8(pk_bf16(e0c.x, e0c.y), pk_bf16(e0c.z, e0c.w),
                       pk_bf16(e1c.x, e1c.y), pk_bf16(e1c.z, e1c.w));
        acc0 = __builtin_amdgcn_mfma_f32_32x32x16_bf16(mk8(a0c.x, a0c.y, a0c.z, a0c.w), B, acc0, 0, 0, 0);
        acc1 = __builtin_amdgcn_mfma_f32_32x32x16_bf16(mk8(a1c.x, a1c.y, a1c.z, a1c.w), B, acc1, 0, 0, 0);
        if (kf < 15) { a0c = a0n; a1c = a1n; e0c = e0n; e1c = e1n; }
    }

    // add bias into acc (classes < 48 only; acc1 regs 8..15 are rows >= 48)
#pragma unroll
    for (int g = 0; g < 4; ++g) {
        acc0[4*g+0] += bb[g].x; acc0[4*g+1] += bb[g].y;
        acc0[4*g+2] += bb[g].z; acc0[4*g+3] += bb[g].w;
    }
#pragma unroll
    for (int g = 0; g < 2; ++g) {
        acc1[4*g+0] += bb[4+g].x; acc1[4*g+1] += bb[4+g].y;
        acc1[4*g+2] += bb[4+g].z; acc1[4*g+3] += bb[4+g].w;
    }

    // write out rows (duplicates across blocks write identical values)
    {
        float* __restrict__ op = out + ((size_t)b * NT + tokc) * NC;
#pragma unroll
        for (int g = 0; g < 4; ++g)
            *(float4*)(op + 8 * g + 4 * h) =
                make_float4(acc0[4*g+0], acc0[4*g+1], acc0[4*g+2], acc0[4*g+3]);
#pragma unroll
        for (int g = 0; g < 2; ++g)
            *(float4*)(op + 32 + 8 * g + 4 * h) =
                make_float4(acc1[4*g+0], acc1[4*g+1], acc1[4*g+2], acc1[4*g+3]);
    }

    float sv = 0.f;
    if (ct == 0) {
        // per-token max over 48 classes: own 24 values + partner lane (h^1)
        float mloc = acc0[0];
#pragma unroll
        for (int r = 1; r < 16; ++r) mloc = fmaxf(mloc, acc0[r]);
#pragma unroll
        for (int r = 0; r < 8; ++r) mloc = fmaxf(mloc, acc1[r]);
        mloc = fmaxf(mloc, __shfl_xor(mloc, 32));
        const float m2 = mloc * L2E;

        // write E row l31 (cols = classes), rows >= 48 zeroed
        float* er = El + l31 * ELD;
#pragma unroll
        for (int reg = 0; reg < 16; ++reg) {
            const int cls = (reg & 3) + 8 * (reg >> 2) + 4 * h;
            er[cls] = exp2f(acc0[reg] * L2E - m2);
        }
#pragma unroll
        for (int reg = 0; reg < 8; ++reg) {
            const int cls = 32 + (reg & 3) + 8 * (reg >> 2) + 4 * h;
            er[cls] = exp2f(acc1[reg] * L2E - m2);
        }
#pragma unroll
        for (int reg = 8; reg < 16; ++reg) {
            const int cls = 32 + (reg & 3) + 8 * (reg >> 2) + 4 * h;
            er[cls] = 0.f;
        }
        if (ELD > 64 && h == 0) {   // pad cols 64..ELD-1
            er[64] = 0.f; er[65] = 0.f; er[66] = 0.f; er[67] = 0.f;
        }
        if (h == 0 && l31 < cl) sv = m2;   // per-row scale (count once)

        // fused numerator emit for this token (valid rows only)
        {
            const int lt = labels[b * NT + tokc];
            float ev = 0.f;
            if (l31 < cl && (((lt >> 2) & 1) == h)) {
                const int rt_sel = lt >> 5;
                const int rr = (lt & 31) - 4 * h;
                const int regidx = (rr & 3) + 4 * (rr >> 3);
                float av = 0.f;
#pragma unroll
                for (int reg = 0; reg < 16; ++reg) {
                    av = (rt_sel == 0 && reg == regidx) ? acc0[reg] : av;
                    av = (rt_sel == 1 && reg == regidx) ? acc1[reg] : av;
                }
                ev = av;   // bias already in acc
            }
#pragma unroll
            for (int o = 32; o; o >>= 1) ev += __shfl_xor(ev, o);
            if (lane == 0) nsum_part[b * NCHUNK + j] = ev;
        }
#pragma unroll
        for (int o = 32; o; o >>= 1) sv += __shfl_xor(sv, o);
        if (lane == 0) svs_sh = sv;
    }
    __syncthreads();

    // ================= SCAN LOOP (r10/r12, verified) =================
    bf16x8 A00 = mkA(trans, l31,      h, 0), A01 = mkA(trans, l31,      h, 1),
           A02 = mkA(trans, l31,      h, 2);
    bf16x8 A10 = mkA(trans, l31 + 32, h, 0), A11 = mkA(trans, l31 + 32, h, 1),
           A12 = mkA(trans, l31 + 32, h, 2);

    f32x16 s_acc0 = mkW(trans, 0, ct, h, l31);
    f32x16 s_acc1 = mkW(trans, 1, ct, h, l31);

    const int nst = cl - 1;   // 31 or 30
#pragma unroll 2
    for (int s = 1; s <= nst; ++s) {
        if (s == 16) {
#pragma unroll
            for (int r = 0; r < 16; ++r) { s_acc0[r] *= 0x1p-88f; s_acc1[r] *= 0x1p-88f; }
        }
        const float* ep = El + (s - 1) * ELD;
        bf16x8 B0, B1, B2;
        MKB1(B0, s_acc0, 0,  0 + 4 * h);
        MKB1(B1, s_acc0, 8, 16 + 4 * h);
        MKB1(B2, s_acc1, 0, 32 + 4 * h);
        f32x16 n0 = mm3(A00, A01, A02, B0, B1, B2);
        f32x16 n1 = mm3(A10, A11, A12, B0, B1, B2);
        s_acc0 = n0; s_acc1 = n1;
    }

    const float* ef = El + nst * ELD;
    scaleRows(s_acc0, ef, 0, h);
    scaleRows(s_acc1, ef, 1, h);

    float m = s_acc0[0];
#pragma unroll
    for (int r = 0; r < 16; ++r) { m = fmaxf(m, s_acc0[r]); m = fmaxf(m, s_acc1[r]); }
#pragma unroll
    for (int o = 32; o; o >>= 1) m = fmaxf(m, __shfl_xor(m, o));
    if (lane == 0) mxs[ct] = m;
    __syncthreads();
    m = fmaxf(mxs[0], mxs[1]);
    const float inv = 1.f / m;

    unsigned* cbase = Cpk + (((size_t)b * NCHUNK + j) << 11);
    storeQ(cbase, s_acc0, inv, 0, ct, h, l31);
    storeQ(cbase, s_acc1, inv, 1, ct, h, l31);

    if (tid == 0) S2tab[b * NCHUNK + j] = svs_sh + 88.f + log2f(m);
}

// ---------------------------------------------------------------------------
// Kernel 3: combine — unchanged loop; numerator = trans-gather + partials
// + t=0 emit.
// ---------------------------------------------------------------------------
__device__ __forceinline__ void comb_load(const unsigned* __restrict__ cb, int k,
                                          uint4* __restrict__ buf) {
    const uint4* p = (const uint4*)(cb + (size_t)k * 2048);
#pragma unroll
    for (int q = 0; q < 12; ++q) buf[q] = p[q];
}

__device__ __forceinline__ void comb_step(const uint4* __restrict__ buf,
                                          float& a, unsigned sh,
                                          float* __restrict__ ash, int lane) {
    ash[lane] = a;
    __syncthreads();
    float4 av[12];
#pragma unroll
    for (int q = 0; q < 12; ++q) av[q] = *(const float4*)(ash + 4 * q);
    float a0 = 0.f, a1 = 0.f, a2 = 0.f, a3 = 0.f;
#pragma unroll
    for (int q = 0; q < 12; ++q) {
        uint4 u = buf[q];
        a0 = fmaf(__uint_as_float((u.x << sh) & 0xffff0000u), av[q].x, a0);
        a1 = fmaf(__uint_as_float((u.y << sh) & 0xffff0000u), av[q].y, a1);
        a2 = fmaf(__uint_as_float((u.z << sh) & 0xffff0000u), av[q].z, a2);
        a3 = fmaf(__uint_as_float((u.w << sh) & 0xffff0000u), av[q].w, a3);
    }
    a = (a0 + a1) + (a2 + a3);
    __syncthreads();
}

__global__ __launch_bounds__(64) void combine_kernel(
    const int* __restrict__ labels, const float* __restrict__ logits,
    const float* __restrict__ start_t, const float* __restrict__ end_t,
    const float* __restrict__ trans, const unsigned* __restrict__ Cpk,
    const float* __restrict__ S2tab, const float* __restrict__ nsum_part,
    float* __restrict__ out_scalar)
{
    __shared__ __align__(16) float ash[64];
    const int b = blockIdx.x;
    const int lane = threadIdx.x;
    const int* __restrict__ lab = labels + b * NT;
    const float* __restrict__ lgp = logits + (size_t)b * NT * NC;

    // numerator: transition-sum + per-chunk emit partials (t=1..1023)
    float nsum = 0.f;
#pragma unroll
    for (int i = 0; i < NT / 64; ++i) {
        const int t = i * 64 + lane;
        if (t > 0) nsum += trans[lab[t - 1] * NC + lab[t]];
    }
    if (lane < NCHUNK) nsum += nsum_part[b * NCHUNK + lane];
#pragma unroll
    for (int o = 32; o; o >>= 1) nsum += __shfl_xor(nsum, o);

    // forward: a0, then 32 chunk matvecs
    float a = (lane < NC) ? exp2f((start_t[lane] + lgp[lane]) * L2E) : 0.f;
    float S2 = 0.f;
    const unsigned sh = (lane & 1) ? 0u : 16u;
    const unsigned* cb = Cpk + (((size_t)b * NCHUNK) << 11) + (lane >> 1) * 64;

    uint4 bufA[12], bufB[12];
    comb_load(cb, 0, bufA);
#pragma unroll 1
    for (int k = 0; k < NCHUNK; k += 2) {
        if (k + 1 < NCHUNK) comb_load(cb, k + 1, bufB);
        comb_step(bufA, a, sh, ash, lane);
        if (k + 2 < NCHUNK) comb_load(cb, k + 2, bufA);
        comb_step(bufB, a, sh, ash, lane);
        if ((k & 7) == 6) {   // rescale every 8 chunk-steps
            float mm = a;
#pragma unroll
            for (int o = 32; o; o >>= 1) mm = fmaxf(mm, __shfl_xor(mm, o));
            a *= 1.f / mm;
            S2 += log2f(mm);
        }
    }

    float pe = (lane < NC) ? a * exp2f(end_t[lane] * L2E) : 0.f;
#pragma unroll
    for (int o = 32; o; o >>= 1) pe += __shfl_xor(pe, o);
    float s2k = (lane < NCHUNK) ? S2tab[b * NCHUNK + lane] : 0.f;
#pragma unroll
    for (int o = 32; o; o >>= 1) s2k += __shfl_xor(s2k, o);

    if (lane == 0) {
        const float logz = (S2 + s2k + log2f(pe)) * LN2;
        // + t=0 emit (not covered by chunk partials)
        const float numer = nsum + lgp[lab[0]] + start_t[lab[0]] + end_t[lab[NT - 1]];
        atomicAdd(out_scalar, logz - numer);
    }
}

// ---------------------------------------------------------------------------
extern "C" void kernel_launch(void* const* d_in, const int* in_sizes, int n_in,
                              void* d_out, int out_size, void* d_ws, size_t ws_size,
                              hipStream_t stream) {
    const int*   x       = (const int*)d_in[0];
    const int*   labels  = (const int*)d_in[1];
    const float* emb     = (const float*)d_in[2];
    const float* fc_w    = (const float*)d_in[3];
    const float* fc_b    = (const float*)d_in[4];
    const float* start_t = (const float*)d_in[5];
    const float* end_t   = (const float*)d_in[6];
    const float* trans   = (const float*)d_in[7];

    float* out = (float*)d_out;
    float* out_scalar = out + (size_t)NB * NT * NC;

    char* ws = (char*)d_ws;
    constexpr size_t CP_BYTES = (size_t)NB * NCHUNK * 2048 * 4;   // 16 MB
    constexpr size_t S2_BYTES = (size_t)NB * NCHUNK * 4;          // 8 KB
    constexpr size_t NP_BYTES = (size_t)NB * NCHUNK * 4;          // 8 KB
    unsigned* Cpk       = (unsigned*)ws;
    float*    S2tab     = (float*)(ws + CP_BYTES);
    float*    nsum_part = (float*)(ws + CP_BYTES + S2_BYTES);
    uint4*    Wfrag     = (uint4*)(ws + CP_BYTES + S2_BYTES + NP_BYTES); // 32 KB

    prep_kernel<<<1, 256, 0, stream>>>(fc_w, Wfrag, out_scalar);
    scan_kernel<<<dim3(NCHUNK, NB), 128, 0, stream>>>(trans, x, labels, emb, fc_b,
                                                      Wfrag, out, nsum_part, Cpk, S2tab);
    combine_kernel<<<NB, 64, 0, stream>>>(labels, out, start_t, end_t, trans,
                                          Cpk, S2tab, nsum_part, out_scalar);
}

// Round 17
// 71.275 us; speedup vs baseline: 1.1688x; 1.1688x over previous
//
#include <hip/hip_runtime.h>
#include <hip/hip_bf16.h>
#include <math.h>

#define NV 50257
#define NE 256
#define NC 48
#define NB 64
#define NT 1024
#define NCHUNK 32          // 31 chunks x 32 factors + 1 chunk x 31 = 1023
#define ELD 68             // scan El row stride (floats)
#define L2E 1.44269504088896340736f
#define LN2 0.69314718055994530942f

typedef __attribute__((ext_vector_type(8)))  short bf16x8;
typedef __attribute__((ext_vector_type(16))) float f32x16;

__device__ __forceinline__ unsigned pk_bf16(float lo, float hi) {
    unsigned r;
    asm("v_cvt_pk_bf16_f32 %0, %1, %2" : "=v"(r) : "v"(lo), "v"(hi));
    return r;
}
__device__ __forceinline__ bf16x8 mk8(unsigned u0, unsigned u1, unsigned u2, unsigned u3) {
    union { unsigned u[4]; bf16x8 v; } t;
    t.u[0] = u0; t.u[1] = u1; t.u[2] = u2; t.u[3] = u3;
    return t.v;
}

// ---------------------------------------------------------------------------
// Kernel 1: logits via MFMA, coalesced staging (r12/r15, passed) + fused
// numerator emit-sum (r15, passed).
// ---------------------------------------------------------------------------
__global__ __launch_bounds__(256) void logits_kernel(
    const int* __restrict__ x, const int* __restrict__ labels,
    const float* __restrict__ emb,
    const float* __restrict__ w, const float* __restrict__ bias,
    float* __restrict__ out, float* __restrict__ nsum_part,
    float* __restrict__ out_scalar)
{
    __shared__ __align__(16) uint4 Wf[2048];            // 32 KB
    __shared__ __align__(16) unsigned Ebf[2][128 * 18]; // 2 x 9 KB

    const int tid = threadIdx.x;
    if (blockIdx.x == 0 && tid == 0) *out_scalar = 0.f;

    // ---- stage W fragments (verified r11/r12) ----
#pragma unroll
    for (int i = 0; i < 8; ++i) {
        const int f = i * 256 + tid;
        const int lane_ = f & 63;
        const int rt_ = (f >> 6) & 1;
        const int kf_ = f >> 7;
        const int r = (lane_ & 31) + 32 * rt_;
        const int h_ = lane_ >> 5;
        uint4 u = make_uint4(0u, 0u, 0u, 0u);
        if (r < NC) {
            const float* wr = w + r * NE + 16 * kf_ + 4 * h_;
            float4 w0 = *(const float4*)(wr);
            float4 w1 = *(const float4*)(wr + 8);
            u.x = pk_bf16(w0.x, w0.y); u.y = pk_bf16(w0.z, w0.w);
            u.z = pk_bf16(w1.x, w1.y); u.w = pk_bf16(w1.z, w1.w);
        }
        Wf[f] = u;
    }

    // ---- E staging geometry: thread covers 4 tokens x 1 quad each ----
    const int tloc = tid >> 3;          // 0..31
    const int q    = tid & 7;           // float4 quad within an eighth
    const float4* rp[4];
#pragma unroll
    for (int i = 0; i < 4; ++i) {
        const int gt = blockIdx.x * 128 + i * 32 + tloc;
        rp[i] = (const float4*)(emb + (size_t)x[gt] * NE) + q;
    }

    const int wv = tid >> 6;
    const int lane = tid & 63;
    const int l31 = lane & 31, h = lane >> 5;
    const int t = blockIdx.x * 128 + wv * 32 + l31;     // this lane's token
    const int t18 = (wv * 32 + l31) * 18;

    float4 bb[6];
#pragma unroll
    for (int g = 0; g < 4; ++g) bb[g] = *(const float4*)(bias + 8 * g + 4 * h);
#pragma unroll
    for (int g = 0; g < 2; ++g) bb[4 + g] = *(const float4*)(bias + 32 + 8 * g + 4 * h);

    f32x16 acc0, acc1;
#pragma unroll
    for (int i = 0; i < 16; ++i) { acc0[i] = 0.f; acc1[i] = 0.f; }

    // prologue: eighth 0 -> buf0
    float4 st[4];
#pragma unroll
    for (int i = 0; i < 4; ++i) st[i] = rp[i][0];
#pragma unroll
    for (int i = 0; i < 4; ++i) {
        uint2 u = make_uint2(pk_bf16(st[i].x, st[i].y), pk_bf16(st[i].z, st[i].w));
        *(uint2*)&Ebf[0][(i * 32 + tloc) * 18 + 2 * q] = u;
    }

#pragma unroll 1
    for (int e = 0; e < 8; ++e) {
        __syncthreads();                 // buf[e&1] writes visible
        if (e < 7) {
#pragma unroll
            for (int i = 0; i < 4; ++i) st[i] = rp[i][8 * (e + 1)];
        }
        const unsigned* eb = &Ebf[e & 1][t18];
#pragma unroll
        for (int kp = 0; kp < 2; ++kp) {
            const int kf = 2 * e + kp;
            uint2 eA = *(const uint2*)(eb + 8 * kp + 2 * h);
            uint2 eB = *(const uint2*)(eb + 8 * kp + 2 * h + 4);
            bf16x8 B = mk8(eA.x, eA.y, eB.x, eB.y);
            uint4 a0 = Wf[kf * 128 + lane];
            uint4 a1 = Wf[kf * 128 + 64 + lane];
            acc0 = __builtin_amdgcn_mfma_f32_32x32x16_bf16(mk8(a0.x, a0.y, a0.z, a0.w), B, acc0, 0, 0, 0);
            acc1 = __builtin_amdgcn_mfma_f32_32x32x16_bf16(mk8(a1.x, a1.y, a1.z, a1.w), B, acc1, 0, 0, 0);
        }
        __syncthreads();                 // all reads of buf[e&1] done
        if (e < 7) {
#pragma unroll
            for (int i = 0; i < 4; ++i) {
                uint2 u = make_uint2(pk_bf16(st[i].x, st[i].y), pk_bf16(st[i].z, st[i].w));
                *(uint2*)&Ebf[(e + 1) & 1][(i * 32 + tloc) * 18 + 2 * q] = u;
            }
        }
    }

    // epilogue: stores (+bias)
    float* __restrict__ op = out + (size_t)t * NC;
#pragma unroll
    for (int g = 0; g < 4; ++g) {
        float4 v = make_float4(acc0[4*g+0] + bb[g].x, acc0[4*g+1] + bb[g].y,
                               acc0[4*g+2] + bb[g].z, acc0[4*g+3] + bb[g].w);
        *(float4*)(op + 8 * g + 4 * h) = v;
    }
#pragma unroll
    for (int g = 0; g < 2; ++g) {
        float4 v = make_float4(acc1[4*g+0] + bb[4+g].x, acc1[4*g+1] + bb[4+g].y,
                               acc1[4*g+2] + bb[4+g].z, acc1[4*g+3] + bb[4+g].w);
        *(float4*)(op + 32 + 8 * g + 4 * h) = v;
    }

    // ---- fused numerator emit: logits[t][labels[t]] (+bias) ----
    {
        const int lt = labels[t];                 // this lane's token label
        float ev = 0.f;
        if (((lt >> 2) & 1) == h) {               // h-parity: this lane holds row lt
            const int rt_sel = lt >> 5;           // acc0 / acc1
            const int rr = (lt & 31) - 4 * h;     // in {0..3,8..11,16..19,24..27}
            const int regidx = (rr & 3) + 4 * (rr >> 3);
            float av = 0.f;
#pragma unroll
            for (int reg = 0; reg < 16; ++reg) {  // compile-time-indexed selects
                av = (rt_sel == 0 && reg == regidx) ? acc0[reg] : av;
                av = (rt_sel == 1 && reg == regidx) ? acc1[reg] : av;
            }
            ev = av + bias[lt];
        }
#pragma unroll
        for (int o = 32; o; o >>= 1) ev += __shfl_xor(ev, o);
        if (lane == 0) nsum_part[blockIdx.x * 4 + wv] = ev;
    }
}

// ---------------------------------------------------------------------------
// Kernel 2: chunked matrix scan — r10/r15 structure; ONLY change:
// __launch_bounds__(128, 4) to raise residency (occupancy was ~2.4/SIMD).
// ---------------------------------------------------------------------------
__device__ __forceinline__ bf16x8 mkA(const float* __restrict__ trans, int r, int h, int kf) {
    unsigned u[4];
#pragma unroll
    for (int p = 0; p < 4; ++p) {
        const int i0 = 2 * p;
        const int k0 = 16 * kf + 4 * h + (i0 & 3) + 8 * (i0 >> 2);
        const int k1 = k0 + 1;
        float v0 = (r < NC && k0 < NC) ? exp2f(trans[k0 * NC + r] * L2E) : 0.f;
        float v1 = (r < NC && k1 < NC) ? exp2f(trans[k1 * NC + r] * L2E) : 0.f;
        u[p] = pk_bf16(v0, v1);
    }
    return mk8(u[0], u[1], u[2], u[3]);
}

__device__ __forceinline__ f32x16 mkW(const float* __restrict__ trans, int rt, int ct, int h, int l31) {
    f32x16 r;
#pragma unroll
    for (int reg = 0; reg < 16; ++reg) {
        const int rw = 32 * rt + (reg & 3) + 8 * (reg >> 2) + 4 * h;
        const int cc = 32 * ct + l31;
        r[reg] = (rw < NC && cc < NC) ? exp2f(trans[cc * NC + rw] * L2E) : 0.f;
    }
    return r;
}

__device__ __forceinline__ f32x16 mm3(bf16x8 a0, bf16x8 a1, bf16x8 a2,
                                      bf16x8 b0, bf16x8 b1, bf16x8 b2) {
    f32x16 z;
#pragma unroll
    for (int i = 0; i < 16; ++i) z[i] = 0.f;
    f32x16 d = __builtin_amdgcn_mfma_f32_32x32x16_bf16(a0, b0, z, 0, 0, 0);
    d = __builtin_amdgcn_mfma_f32_32x32x16_bf16(a1, b1, d, 0, 0, 0);
    d = __builtin_amdgcn_mfma_f32_32x32x16_bf16(a2, b2, d, 0, 0, 0);
    return d;
}

__device__ __forceinline__ void scaleRows(f32x16& A, const float* ef, int rt, int h) {
#pragma unroll
    for (int g = 0; g < 4; ++g) {
        float4 e = *(const float4*)(ef + 32 * rt + 8 * g + 4 * h);
        A[4*g+0] *= e.x; A[4*g+1] *= e.y; A[4*g+2] *= e.z; A[4*g+3] *= e.w;
    }
}

__device__ __forceinline__ void storeQ(unsigned* __restrict__ cbase, const f32x16& A,
                                       float inv, int rt, int ct, int h, int l31) {
#pragma unroll
    for (int g = 0; g < 4; ++g)
#pragma unroll
        for (int pp = 0; pp < 2; ++pp) {
            const int reg = 4 * g + 2 * pp;
            unsigned u = pk_bf16(A[reg] * inv, A[reg + 1] * inv);
            const int rw = 32 * rt + 2 * pp + 8 * g + 4 * h;
            cbase[(rw >> 1) * 64 + 32 * ct + l31] = u;
        }
}

#define MKB1(BD, S, q, eo)                                                \
  {                                                                       \
    float4 _e0 = *(const float4*)(ep + (eo));                             \
    float4 _e1 = *(const float4*)(ep + (eo) + 8);                         \
    unsigned _u0 = pk_bf16(S[(q)+0]*_e0.x, S[(q)+1]*_e0.y);               \
    unsigned _u1 = pk_bf16(S[(q)+2]*_e0.z, S[(q)+3]*_e0.w);               \
    unsigned _u2 = pk_bf16(S[(q)+4]*_e1.x, S[(q)+5]*_e1.y);               \
    unsigned _u3 = pk_bf16(S[(q)+6]*_e1.z, S[(q)+7]*_e1.w);               \
    BD = mk8(_u0, _u1, _u2, _u3);                                         \
  }

__global__ __launch_bounds__(128, 4) void scan_kernel(
    const float* __restrict__ trans, const float* __restrict__ logits,
    unsigned* __restrict__ Cpk, float* __restrict__ S2tab)
{
    const int j = blockIdx.x;          // chunk
    const int b = blockIdx.y;          // batch
    const int tid = threadIdx.x;
    const int ct = tid >> 6;           // wave = column half
    const int lane = tid & 63;
    const int h = lane >> 5, l31 = lane & 31;
    const int t0 = j * 32;
    const int cl = (j == NCHUNK - 1) ? 31 : 32;

    __shared__ __align__(16) float El[32 * ELD];
    __shared__ float mxs[2], svs[2];

    // ---- stage E rows (4 lanes per row, 12 cols each), row-max normalized ----
    const int row = tid >> 2, cs = tid & 3;
    float s2v = 0.f;
    {
        float e[12];
        float mloc = -3.0e38f;
        if (row < cl) {
            const float* lr = logits + ((size_t)b * NT + t0 + 1 + row) * NC + cs * 12;
            float4 v0 = *(const float4*)(lr + 0);
            float4 v1 = *(const float4*)(lr + 4);
            float4 v2 = *(const float4*)(lr + 8);
            e[0]=v0.x; e[1]=v0.y; e[2]=v0.z;  e[3]=v0.w;
            e[4]=v1.x; e[5]=v1.y; e[6]=v1.z;  e[7]=v1.w;
            e[8]=v2.x; e[9]=v2.y; e[10]=v2.z; e[11]=v2.w;
#pragma unroll
            for (int qq = 0; qq < 12; ++qq) mloc = fmaxf(mloc, e[qq]);
        }
        mloc = fmaxf(mloc, __shfl_xor(mloc, 1));
        mloc = fmaxf(mloc, __shfl_xor(mloc, 2));
        const float m2 = mloc * L2E;
        float* er = El + row * ELD;
        if (row < cl) {
#pragma unroll
            for (int qq = 0; qq < 12; ++qq) er[cs * 12 + qq] = exp2f(e[qq] * L2E - m2);
            if (cs == 0) s2v = m2;
        }
        if (cs == 3) {   // zero-pad cols 48..67 (zero K>=48 + NaN-safety)
            *(float4*)(er + 48) = make_float4(0.f, 0.f, 0.f, 0.f);
            *(float4*)(er + 52) = make_float4(0.f, 0.f, 0.f, 0.f);
            *(float4*)(er + 56) = make_float4(0.f, 0.f, 0.f, 0.f);
            *(float4*)(er + 60) = make_float4(0.f, 0.f, 0.f, 0.f);
            *(float4*)(er + 64) = make_float4(0.f, 0.f, 0.f, 0.f);
        }
    }
    __syncthreads();

    // ---- constant A = P^T frags, K=48 (kf 0..2); acc init = own col half ----
    bf16x8 A00 = mkA(trans, l31,      h, 0), A01 = mkA(trans, l31,      h, 1),
           A02 = mkA(trans, l31,      h, 2);
    bf16x8 A10 = mkA(trans, l31 + 32, h, 0), A11 = mkA(trans, l31 + 32, h, 1),
           A12 = mkA(trans, l31 + 32, h, 2);

    f32x16 acc0 = mkW(trans, 0, ct, h, l31);
    f32x16 acc1 = mkW(trans, 1, ct, h, l31);

    const int nst = cl - 1;   // 31 or 30
#pragma unroll 2
    for (int s = 1; s <= nst; ++s) {
        if (s == 16) {   // static range shift (validated in r3)
#pragma unroll
            for (int r = 0; r < 16; ++r) { acc0[r] *= 0x1p-88f; acc1[r] *= 0x1p-88f; }
        }
        const float* ep = El + (s - 1) * ELD;
        bf16x8 B0, B1, B2;
        MKB1(B0, acc0, 0,  0 + 4 * h);   // k =  0..15
        MKB1(B1, acc0, 8, 16 + 4 * h);   // k = 16..31
        MKB1(B2, acc1, 0, 32 + 4 * h);   // k = 32..47  (k>=48: E==0, dropped)
        f32x16 n0 = mm3(A00, A01, A02, B0, B1, B2);
        f32x16 n1 = mm3(A10, A11, A12, B0, B1, B2);
        acc0 = n0; acc1 = n1;
    }

    // final row-scale by E_{t0+cl} (row nst)
    const float* ef = El + nst * ELD;
    scaleRows(acc0, ef, 0, h);
    scaleRows(acc1, ef, 1, h);

    // block max (cross-wave via LDS) + per-row scale sum
    float m = acc0[0];
#pragma unroll
    for (int r = 0; r < 16; ++r) { m = fmaxf(m, acc0[r]); m = fmaxf(m, acc1[r]); }
#pragma unroll
    for (int o = 32; o; o >>= 1) m = fmaxf(m, __shfl_xor(m, o));
    float sv = s2v;
#pragma unroll
    for (int o = 32; o; o >>= 1) sv += __shfl_xor(sv, o);
    if (lane == 0) { mxs[ct] = m; svs[ct] = sv; }
    __syncthreads();
    m = fmaxf(mxs[0], mxs[1]);
    const float inv = 1.f / m;

    unsigned* cbase = Cpk + (((size_t)b * NCHUNK + j) << 11);
    storeQ(cbase, acc0, inv, 0, ct, h, l31);
    storeQ(cbase, acc1, inv, 1, ct, h, l31);

    if (tid == 0) S2tab[b * NCHUNK + j] = svs[0] + svs[1] + 88.f + log2f(m);
}

// ---------------------------------------------------------------------------
// Kernel 3: combine — r15 (passed).
// ---------------------------------------------------------------------------
__device__ __forceinline__ void comb_load(const unsigned* __restrict__ cb, int k,
                                          uint4* __restrict__ buf) {
    const uint4* p = (const uint4*)(cb + (size_t)k * 2048);
#pragma unroll
    for (int q = 0; q < 12; ++q) buf[q] = p[q];
}

__device__ __forceinline__ void comb_step(const uint4* __restrict__ buf,
                                          float& a, unsigned sh,
                                          float* __restrict__ ash, int lane) {
    ash[lane] = a;
    __syncthreads();
    float4 av[12];
#pragma unroll
    for (int q = 0; q < 12; ++q) av[q] = *(const float4*)(ash + 4 * q);
    float a0 = 0.f, a1 = 0.f, a2 = 0.f, a3 = 0.f;
#pragma unroll
    for (int q = 0; q < 12; ++q) {
        uint4 u = buf[q];
        a0 = fmaf(__uint_as_float((u.x << sh) & 0xffff0000u), av[q].x, a0);
        a1 = fmaf(__uint_as_float((u.y << sh) & 0xffff0000u), av[q].y, a1);
        a2 = fmaf(__uint_as_float((u.z << sh) & 0xffff0000u), av[q].z, a2);
        a3 = fmaf(__uint_as_float((u.w << sh) & 0xffff0000u), av[q].w, a3);
    }
    a = (a0 + a1) + (a2 + a3);
    __syncthreads();
}

__global__ __launch_bounds__(64) void combine_kernel(
    const int* __restrict__ labels, const float* __restrict__ logits,
    const float* __restrict__ start_t, const float* __restrict__ end_t,
    const float* __restrict__ trans, const unsigned* __restrict__ Cpk,
    const float* __restrict__ S2tab, const float* __restrict__ nsum_part,
    float* __restrict__ out_scalar)
{
    __shared__ __align__(16) float ash[64];
    const int b = blockIdx.x;
    const int lane = threadIdx.x;
    const int* __restrict__ lab = labels + b * NT;
    const float* __restrict__ lgp = logits + (size_t)b * NT * NC;

    // numerator: transition-sum only (emit sum fused into logits kernel)
    float nsum = 0.f;
#pragma unroll
    for (int i = 0; i < NT / 64; ++i) {
        const int t = i * 64 + lane;
        if (t > 0) nsum += trans[lab[t - 1] * NC + lab[t]];
    }
    if (lane < 32) nsum += nsum_part[b * 32 + lane];
#pragma unroll
    for (int o = 32; o; o >>= 1) nsum += __shfl_xor(nsum, o);

    // forward: a0, then 32 chunk matvecs
    float a = (lane < NC) ? exp2f((start_t[lane] + lgp[lane]) * L2E) : 0.f;
    float S2 = 0.f;
    const unsigned sh = (lane & 1) ? 0u : 16u;
    const unsigned* cb = Cpk + (((size_t)b * NCHUNK) << 11) + (lane >> 1) * 64;

    uint4 bufA[12], bufB[12];
    comb_load(cb, 0, bufA);
#pragma unroll 1
    for (int k = 0; k < NCHUNK; k += 2) {
        if (k + 1 < NCHUNK) comb_load(cb, k + 1, bufB);
        comb_step(bufA, a, sh, ash, lane);
        if (k + 2 < NCHUNK) comb_load(cb, k + 2, bufA);
        comb_step(bufB, a, sh, ash, lane);
        if ((k & 7) == 6) {   // rescale every 8 chunk-steps
            float mm = a;
#pragma unroll
            for (int o = 32; o; o >>= 1) mm = fmaxf(mm, __shfl_xor(mm, o));
            a *= 1.f / mm;
            S2 += log2f(mm);
        }
    }

    float pe = (lane < NC) ? a * exp2f(end_t[lane] * L2E) : 0.f;
#pragma unroll
    for (int o = 32; o; o >>= 1) pe += __shfl_xor(pe, o);
    float s2k = (lane < NCHUNK) ? S2tab[b * NCHUNK + lane] : 0.f;
#pragma unroll
    for (int o = 32; o; o >>= 1) s2k += __shfl_xor(s2k, o);

    if (lane == 0) {
        const float logz = (S2 + s2k + log2f(pe)) * LN2;
        const float numer = nsum + start_t[lab[0]] + end_t[lab[NT - 1]];
        atomicAdd(out_scalar, logz - numer);
    }
}

// ---------------------------------------------------------------------------
extern "C" void kernel_launch(void* const* d_in, const int* in_sizes, int n_in,
                              void* d_out, int out_size, void* d_ws, size_t ws_size,
                              hipStream_t stream) {
    const int*   x       = (const int*)d_in[0];
    const int*   labels  = (const int*)d_in[1];
    const float* emb     = (const float*)d_in[2];
    const float* fc_w    = (const float*)d_in[3];
    const float* fc_b    = (const float*)d_in[4];
    const float* start_t = (const float*)d_in[5];
    const float* end_t   = (const float*)d_in[6];
    const float* trans   = (const float*)d_in[7];

    float* out = (float*)d_out;
    float* out_scalar = out + (size_t)NB * NT * NC;

    char* ws = (char*)d_ws;
    constexpr size_t CP_BYTES = (size_t)NB * NCHUNK * 2048 * 4;   // 16 MB
    constexpr size_t S2_BYTES = (size_t)NB * NCHUNK * 4;          // 8 KB
    unsigned* Cpk       = (unsigned*)ws;
    float*    S2tab     = (float*)(ws + CP_BYTES);
    float*    nsum_part = (float*)(ws + CP_BYTES + S2_BYTES);     // 2048 floats

    logits_kernel<<<NB * NT / 128, 256, 0, stream>>>(x, labels, emb, fc_w, fc_b,
                                                     out, nsum_part, out_scalar);
    scan_kernel<<<dim3(NCHUNK, NB), 128, 0, stream>>>(trans, out, Cpk, S2tab);
    combine_kernel<<<NB, 64, 0, stream>>>(labels, out, start_t, end_t, trans,
                                          Cpk, S2tab, nsum_part, out_scalar);
}

// Round 18
// 62.766 us; speedup vs baseline: 1.3273x; 1.1356x over previous
//
#include <hip/hip_runtime.h>
#include <hip/hip_bf16.h>
#include <math.h>

#define NV 50257
#define NE 256
#define NC 48
#define NB 64
#define NT 1024
#define NCHUNK 16          // 15 chunks x 64 factors + 1 chunk x 63 = 1023
#define ELD 68             // scan El row stride (floats)
#define L2E 1.44269504088896340736f
#define LN2 0.69314718055994530942f

typedef __attribute__((ext_vector_type(8)))  short bf16x8;
typedef __attribute__((ext_vector_type(16))) float f32x16;

__device__ __forceinline__ unsigned pk_bf16(float lo, float hi) {
    unsigned r;
    asm("v_cvt_pk_bf16_f32 %0, %1, %2" : "=v"(r) : "v"(lo), "v"(hi));
    return r;
}
__device__ __forceinline__ bf16x8 mk8(unsigned u0, unsigned u1, unsigned u2, unsigned u3) {
    union { unsigned u[4]; bf16x8 v; } t;
    t.u[0] = u0; t.u[1] = u1; t.u[2] = u2; t.u[3] = u3;
    return t.v;
}

// ---------------------------------------------------------------------------
// Kernel 1: logits via MFMA, coalesced staging + fused emit-sum (r15, passed).
// ---------------------------------------------------------------------------
__global__ __launch_bounds__(256) void logits_kernel(
    const int* __restrict__ x, const int* __restrict__ labels,
    const float* __restrict__ emb,
    const float* __restrict__ w, const float* __restrict__ bias,
    float* __restrict__ out, float* __restrict__ nsum_part,
    float* __restrict__ out_scalar)
{
    __shared__ __align__(16) uint4 Wf[2048];            // 32 KB
    __shared__ __align__(16) unsigned Ebf[2][128 * 18]; // 2 x 9 KB

    const int tid = threadIdx.x;
    if (blockIdx.x == 0 && tid == 0) *out_scalar = 0.f;

#pragma unroll
    for (int i = 0; i < 8; ++i) {
        const int f = i * 256 + tid;
        const int lane_ = f & 63;
        const int rt_ = (f >> 6) & 1;
        const int kf_ = f >> 7;
        const int r = (lane_ & 31) + 32 * rt_;
        const int h_ = lane_ >> 5;
        uint4 u = make_uint4(0u, 0u, 0u, 0u);
        if (r < NC) {
            const float* wr = w + r * NE + 16 * kf_ + 4 * h_;
            float4 w0 = *(const float4*)(wr);
            float4 w1 = *(const float4*)(wr + 8);
            u.x = pk_bf16(w0.x, w0.y); u.y = pk_bf16(w0.z, w0.w);
            u.z = pk_bf16(w1.x, w1.y); u.w = pk_bf16(w1.z, w1.w);
        }
        Wf[f] = u;
    }

    const int tloc = tid >> 3;
    const int q    = tid & 7;
    const float4* rp[4];
#pragma unroll
    for (int i = 0; i < 4; ++i) {
        const int gt = blockIdx.x * 128 + i * 32 + tloc;
        rp[i] = (const float4*)(emb + (size_t)x[gt] * NE) + q;
    }

    const int wv = tid >> 6;
    const int lane = tid & 63;
    const int l31 = lane & 31, h = lane >> 5;
    const int t = blockIdx.x * 128 + wv * 32 + l31;
    const int t18 = (wv * 32 + l31) * 18;

    float4 bb[6];
#pragma unroll
    for (int g = 0; g < 4; ++g) bb[g] = *(const float4*)(bias + 8 * g + 4 * h);
#pragma unroll
    for (int g = 0; g < 2; ++g) bb[4 + g] = *(const float4*)(bias + 32 + 8 * g + 4 * h);

    f32x16 acc0, acc1;
#pragma unroll
    for (int i = 0; i < 16; ++i) { acc0[i] = 0.f; acc1[i] = 0.f; }

    float4 st[4];
#pragma unroll
    for (int i = 0; i < 4; ++i) st[i] = rp[i][0];
#pragma unroll
    for (int i = 0; i < 4; ++i) {
        uint2 u = make_uint2(pk_bf16(st[i].x, st[i].y), pk_bf16(st[i].z, st[i].w));
        *(uint2*)&Ebf[0][(i * 32 + tloc) * 18 + 2 * q] = u;
    }

#pragma unroll 1
    for (int e = 0; e < 8; ++e) {
        __syncthreads();
        if (e < 7) {
#pragma unroll
            for (int i = 0; i < 4; ++i) st[i] = rp[i][8 * (e + 1)];
        }
        const unsigned* eb = &Ebf[e & 1][t18];
#pragma unroll
        for (int kp = 0; kp < 2; ++kp) {
            const int kf = 2 * e + kp;
            uint2 eA = *(const uint2*)(eb + 8 * kp + 2 * h);
            uint2 eB = *(const uint2*)(eb + 8 * kp + 2 * h + 4);
            bf16x8 B = mk8(eA.x, eA.y, eB.x, eB.y);
            uint4 a0 = Wf[kf * 128 + lane];
            uint4 a1 = Wf[kf * 128 + 64 + lane];
            acc0 = __builtin_amdgcn_mfma_f32_32x32x16_bf16(mk8(a0.x, a0.y, a0.z, a0.w), B, acc0, 0, 0, 0);
            acc1 = __builtin_amdgcn_mfma_f32_32x32x16_bf16(mk8(a1.x, a1.y, a1.z, a1.w), B, acc1, 0, 0, 0);
        }
        __syncthreads();
        if (e < 7) {
#pragma unroll
            for (int i = 0; i < 4; ++i) {
                uint2 u = make_uint2(pk_bf16(st[i].x, st[i].y), pk_bf16(st[i].z, st[i].w));
                *(uint2*)&Ebf[(e + 1) & 1][(i * 32 + tloc) * 18 + 2 * q] = u;
            }
        }
    }

    float* __restrict__ op = out + (size_t)t * NC;
#pragma unroll
    for (int g = 0; g < 4; ++g) {
        float4 v = make_float4(acc0[4*g+0] + bb[g].x, acc0[4*g+1] + bb[g].y,
                               acc0[4*g+2] + bb[g].z, acc0[4*g+3] + bb[g].w);
        *(float4*)(op + 8 * g + 4 * h) = v;
    }
#pragma unroll
    for (int g = 0; g < 2; ++g) {
        float4 v = make_float4(acc1[4*g+0] + bb[4+g].x, acc1[4*g+1] + bb[4+g].y,
                               acc1[4*g+2] + bb[4+g].z, acc1[4*g+3] + bb[4+g].w);
        *(float4*)(op + 32 + 8 * g + 4 * h) = v;
    }

    // fused numerator emit
    {
        const int lt = labels[t];
        float ev = 0.f;
        if (((lt >> 2) & 1) == h) {
            const int rt_sel = lt >> 5;
            const int rr = (lt & 31) - 4 * h;
            const int regidx = (rr & 3) + 4 * (rr >> 3);
            float av = 0.f;
#pragma unroll
            for (int reg = 0; reg < 16; ++reg) {
                av = (rt_sel == 0 && reg == regidx) ? acc0[reg] : av;
                av = (rt_sel == 1 && reg == regidx) ? acc1[reg] : av;
            }
            ev = av + bias[lt];
        }
#pragma unroll
        for (int o = 32; o; o >>= 1) ev += __shfl_xor(ev, o);
        if (lane == 0) nsum_part[blockIdx.x * 4 + wv] = ev;
    }
}

// ---------------------------------------------------------------------------
// Kernel 2: chunked matrix scan — r10/r15 loop body; NCHUNK=16, CL=64:
// half the blocks (pass count), prologue amortized 2x, shifts at s=16,32,48.
// ---------------------------------------------------------------------------
__device__ __forceinline__ bf16x8 mkA(const float* __restrict__ trans, int r, int h, int kf) {
    unsigned u[4];
#pragma unroll
    for (int p = 0; p < 4; ++p) {
        const int i0 = 2 * p;
        const int k0 = 16 * kf + 4 * h + (i0 & 3) + 8 * (i0 >> 2);
        const int k1 = k0 + 1;
        float v0 = (r < NC && k0 < NC) ? exp2f(trans[k0 * NC + r] * L2E) : 0.f;
        float v1 = (r < NC && k1 < NC) ? exp2f(trans[k1 * NC + r] * L2E) : 0.f;
        u[p] = pk_bf16(v0, v1);
    }
    return mk8(u[0], u[1], u[2], u[3]);
}

__device__ __forceinline__ f32x16 mkW(const float* __restrict__ trans, int rt, int ct, int h, int l31) {
    f32x16 r;
#pragma unroll
    for (int reg = 0; reg < 16; ++reg) {
        const int rw = 32 * rt + (reg & 3) + 8 * (reg >> 2) + 4 * h;
        const int cc = 32 * ct + l31;
        r[reg] = (rw < NC && cc < NC) ? exp2f(trans[cc * NC + rw] * L2E) : 0.f;
    }
    return r;
}

__device__ __forceinline__ f32x16 mm3(bf16x8 a0, bf16x8 a1, bf16x8 a2,
                                      bf16x8 b0, bf16x8 b1, bf16x8 b2) {
    f32x16 z;
#pragma unroll
    for (int i = 0; i < 16; ++i) z[i] = 0.f;
    f32x16 d = __builtin_amdgcn_mfma_f32_32x32x16_bf16(a0, b0, z, 0, 0, 0);
    d = __builtin_amdgcn_mfma_f32_32x32x16_bf16(a1, b1, d, 0, 0, 0);
    d = __builtin_amdgcn_mfma_f32_32x32x16_bf16(a2, b2, d, 0, 0, 0);
    return d;
}

__device__ __forceinline__ void scaleRows(f32x16& A, const float* ef, int rt, int h) {
#pragma unroll
    for (int g = 0; g < 4; ++g) {
        float4 e = *(const float4*)(ef + 32 * rt + 8 * g + 4 * h);
        A[4*g+0] *= e.x; A[4*g+1] *= e.y; A[4*g+2] *= e.z; A[4*g+3] *= e.w;
    }
}

__device__ __forceinline__ void storeQ(unsigned* __restrict__ cbase, const f32x16& A,
                                       float inv, int rt, int ct, int h, int l31) {
#pragma unroll
    for (int g = 0; g < 4; ++g)
#pragma unroll
        for (int pp = 0; pp < 2; ++pp) {
            const int reg = 4 * g + 2 * pp;
            unsigned u = pk_bf16(A[reg] * inv, A[reg + 1] * inv);
            const int rw = 32 * rt + 2 * pp + 8 * g + 4 * h;
            cbase[(rw >> 1) * 64 + 32 * ct + l31] = u;
        }
}

#define MKB1(BD, S, q, eo)                                                \
  {                                                                       \
    float4 _e0 = *(const float4*)(ep + (eo));                             \
    float4 _e1 = *(const float4*)(ep + (eo) + 8);                         \
    unsigned _u0 = pk_bf16(S[(q)+0]*_e0.x, S[(q)+1]*_e0.y);               \
    unsigned _u1 = pk_bf16(S[(q)+2]*_e0.z, S[(q)+3]*_e0.w);               \
    unsigned _u2 = pk_bf16(S[(q)+4]*_e1.x, S[(q)+5]*_e1.y);               \
    unsigned _u3 = pk_bf16(S[(q)+6]*_e1.z, S[(q)+7]*_e1.w);               \
    BD = mk8(_u0, _u1, _u2, _u3);                                         \
  }

__global__ __launch_bounds__(128, 3) void scan_kernel(
    const float* __restrict__ trans, const float* __restrict__ logits,
    unsigned* __restrict__ Cpk, float* __restrict__ S2tab)
{
    const int j = blockIdx.x;          // chunk
    const int b = blockIdx.y;          // batch
    const int tid = threadIdx.x;
    const int ct = tid >> 6;           // wave = column half
    const int lane = tid & 63;
    const int h = lane >> 5, l31 = lane & 31;
    const int t0 = j * 64;
    const int cl = (j == NCHUNK - 1) ? 63 : 64;

    __shared__ __align__(16) float El[64 * ELD];
    __shared__ float mxs[2], svs[2];

    // ---- stage E rows (2 row-groups of 32; 4 lanes per row) ----
    const int row = tid >> 2, cs = tid & 3;
    float s2v = 0.f;
#pragma unroll
    for (int gg = 0; gg < 2; ++gg) {
        const int r2 = row + 32 * gg;
        float e[12];
        float mloc = -3.0e38f;
        if (r2 < cl) {
            const float* lr = logits + ((size_t)b * NT + t0 + 1 + r2) * NC + cs * 12;
            float4 v0 = *(const float4*)(lr + 0);
            float4 v1 = *(const float4*)(lr + 4);
            float4 v2 = *(const float4*)(lr + 8);
            e[0]=v0.x; e[1]=v0.y; e[2]=v0.z;  e[3]=v0.w;
            e[4]=v1.x; e[5]=v1.y; e[6]=v1.z;  e[7]=v1.w;
            e[8]=v2.x; e[9]=v2.y; e[10]=v2.z; e[11]=v2.w;
#pragma unroll
            for (int qq = 0; qq < 12; ++qq) mloc = fmaxf(mloc, e[qq]);
        }
        mloc = fmaxf(mloc, __shfl_xor(mloc, 1));
        mloc = fmaxf(mloc, __shfl_xor(mloc, 2));
        const float m2 = mloc * L2E;
        float* er = El + r2 * ELD;
        if (r2 < cl) {
#pragma unroll
            for (int qq = 0; qq < 12; ++qq) er[cs * 12 + qq] = exp2f(e[qq] * L2E - m2);
            if (cs == 0) s2v += m2;
        }
        if (cs == 3) {   // zero-pad cols 48..67 (zero K>=48 + NaN-safety)
            *(float4*)(er + 48) = make_float4(0.f, 0.f, 0.f, 0.f);
            *(float4*)(er + 52) = make_float4(0.f, 0.f, 0.f, 0.f);
            *(float4*)(er + 56) = make_float4(0.f, 0.f, 0.f, 0.f);
            *(float4*)(er + 60) = make_float4(0.f, 0.f, 0.f, 0.f);
            *(float4*)(er + 64) = make_float4(0.f, 0.f, 0.f, 0.f);
        }
    }
    __syncthreads();

    // ---- constant A = P^T frags, K=48; acc init = own col half of P^T ----
    bf16x8 A00 = mkA(trans, l31,      h, 0), A01 = mkA(trans, l31,      h, 1),
           A02 = mkA(trans, l31,      h, 2);
    bf16x8 A10 = mkA(trans, l31 + 32, h, 0), A11 = mkA(trans, l31 + 32, h, 1),
           A12 = mkA(trans, l31 + 32, h, 2);

    f32x16 acc0 = mkW(trans, 0, ct, h, l31);
    f32x16 acc1 = mkW(trans, 1, ct, h, l31);

    const int nst = cl - 1;   // 63 or 62
#pragma unroll 2
    for (int s = 1; s <= nst; ++s) {
        if ((s & 15) == 0) {   // static range shift at s = 16, 32, 48
#pragma unroll
            for (int r = 0; r < 16; ++r) { acc0[r] *= 0x1p-88f; acc1[r] *= 0x1p-88f; }
        }
        const float* ep = El + (s - 1) * ELD;
        bf16x8 B0, B1, B2;
        MKB1(B0, acc0, 0,  0 + 4 * h);   // k =  0..15
        MKB1(B1, acc0, 8, 16 + 4 * h);   // k = 16..31
        MKB1(B2, acc1, 0, 32 + 4 * h);   // k = 32..47
        f32x16 n0 = mm3(A00, A01, A02, B0, B1, B2);
        f32x16 n1 = mm3(A10, A11, A12, B0, B1, B2);
        acc0 = n0; acc1 = n1;
    }

    // final row-scale by E_{t0+cl} (row nst)
    const float* ef = El + nst * ELD;
    scaleRows(acc0, ef, 0, h);
    scaleRows(acc1, ef, 1, h);

    // block max (cross-wave via LDS) + per-row scale sum
    float m = acc0[0];
#pragma unroll
    for (int r = 0; r < 16; ++r) { m = fmaxf(m, acc0[r]); m = fmaxf(m, acc1[r]); }
#pragma unroll
    for (int o = 32; o; o >>= 1) m = fmaxf(m, __shfl_xor(m, o));
    float sv = s2v;
#pragma unroll
    for (int o = 32; o; o >>= 1) sv += __shfl_xor(sv, o);
    if (lane == 0) { mxs[ct] = m; svs[ct] = sv; }
    __syncthreads();
    m = fmaxf(mxs[0], mxs[1]);
    const float inv = 1.f / m;

    unsigned* cbase = Cpk + (((size_t)b * NCHUNK + j) << 11);
    storeQ(cbase, acc0, inv, 0, ct, h, l31);
    storeQ(cbase, acc1, inv, 1, ct, h, l31);

    // 3 static shifts of 2^-88 -> +264
    if (tid == 0) S2tab[b * NCHUNK + j] = svs[0] + svs[1] + 264.f + log2f(m);
}

// ---------------------------------------------------------------------------
// Kernel 3: combine — 16 chunk matvecs now.
// ---------------------------------------------------------------------------
__device__ __forceinline__ void comb_load(const unsigned* __restrict__ cb, int k,
                                          uint4* __restrict__ buf) {
    const uint4* p = (const uint4*)(cb + (size_t)k * 2048);
#pragma unroll
    for (int q = 0; q < 12; ++q) buf[q] = p[q];
}

__device__ __forceinline__ void comb_step(const uint4* __restrict__ buf,
                                          float& a, unsigned sh,
                                          float* __restrict__ ash, int lane) {
    ash[lane] = a;
    __syncthreads();
    float4 av[12];
#pragma unroll
    for (int q = 0; q < 12; ++q) av[q] = *(const float4*)(ash + 4 * q);
    float a0 = 0.f, a1 = 0.f, a2 = 0.f, a3 = 0.f;
#pragma unroll
    for (int q = 0; q < 12; ++q) {
        uint4 u = buf[q];
        a0 = fmaf(__uint_as_float((u.x << sh) & 0xffff0000u), av[q].x, a0);
        a1 = fmaf(__uint_as_float((u.y << sh) & 0xffff0000u), av[q].y, a1);
        a2 = fmaf(__uint_as_float((u.z << sh) & 0xffff0000u), av[q].z, a2);
        a3 = fmaf(__uint_as_float((u.w << sh) & 0xffff0000u), av[q].w, a3);
    }
    a = (a0 + a1) + (a2 + a3);
    __syncthreads();
}

__global__ __launch_bounds__(64) void combine_kernel(
    const int* __restrict__ labels, const float* __restrict__ logits,
    const float* __restrict__ start_t, const float* __restrict__ end_t,
    const float* __restrict__ trans, const unsigned* __restrict__ Cpk,
    const float* __restrict__ S2tab, const float* __restrict__ nsum_part,
    float* __restrict__ out_scalar)
{
    __shared__ __align__(16) float ash[64];
    const int b = blockIdx.x;
    const int lane = threadIdx.x;
    const int* __restrict__ lab = labels + b * NT;
    const float* __restrict__ lgp = logits + (size_t)b * NT * NC;

    // numerator: transition-sum + emit partials (fused in logits kernel)
    float nsum = 0.f;
#pragma unroll
    for (int i = 0; i < NT / 64; ++i) {
        const int t = i * 64 + lane;
        if (t > 0) nsum += trans[lab[t - 1] * NC + lab[t]];
    }
    if (lane < 32) nsum += nsum_part[b * 32 + lane];
#pragma unroll
    for (int o = 32; o; o >>= 1) nsum += __shfl_xor(nsum, o);

    // forward: a0, then 16 chunk matvecs
    float a = (lane < NC) ? exp2f((start_t[lane] + lgp[lane]) * L2E) : 0.f;
    float S2 = 0.f;
    const unsigned sh = (lane & 1) ? 0u : 16u;
    const unsigned* cb = Cpk + (((size_t)b * NCHUNK) << 11) + (lane >> 1) * 64;

    uint4 bufA[12], bufB[12];
    comb_load(cb, 0, bufA);
#pragma unroll 1
    for (int k = 0; k < NCHUNK; k += 2) {
        if (k + 1 < NCHUNK) comb_load(cb, k + 1, bufB);
        comb_step(bufA, a, sh, ash, lane);
        if (k + 2 < NCHUNK) comb_load(cb, k + 2, bufA);
        comb_step(bufB, a, sh, ash, lane);
        if ((k & 7) == 6) {   // rescale every 8 chunk-steps
            float mm = a;
#pragma unroll
            for (int o = 32; o; o >>= 1) mm = fmaxf(mm, __shfl_xor(mm, o));
            a *= 1.f / mm;
            S2 += log2f(mm);
        }
    }

    float pe = (lane < NC) ? a * exp2f(end_t[lane] * L2E) : 0.f;
#pragma unroll
    for (int o = 32; o; o >>= 1) pe += __shfl_xor(pe, o);
    float s2k = (lane < NCHUNK) ? S2tab[b * NCHUNK + lane] : 0.f;
#pragma unroll
    for (int o = 32; o; o >>= 1) s2k += __shfl_xor(s2k, o);

    if (lane == 0) {
        const float logz = (S2 + s2k + log2f(pe)) * LN2;
        const float numer = nsum + start_t[lab[0]] + end_t[lab[NT - 1]];
        atomicAdd(out_scalar, logz - numer);
    }
}

// ---------------------------------------------------------------------------
extern "C" void kernel_launch(void* const* d_in, const int* in_sizes, int n_in,
                              void* d_out, int out_size, void* d_ws, size_t ws_size,
                              hipStream_t stream) {
    const int*   x       = (const int*)d_in[0];
    const int*   labels  = (const int*)d_in[1];
    const float* emb     = (const float*)d_in[2];
    const float* fc_w    = (const float*)d_in[3];
    const float* fc_b    = (const float*)d_in[4];
    const float* start_t = (const float*)d_in[5];
    const float* end_t   = (const float*)d_in[6];
    const float* trans   = (const float*)d_in[7];

    float* out = (float*)d_out;
    float* out_scalar = out + (size_t)NB * NT * NC;

    char* ws = (char*)d_ws;
    constexpr size_t CP_BYTES = (size_t)NB * NCHUNK * 2048 * 4;   // 8 MB
    constexpr size_t S2_BYTES = (size_t)NB * NCHUNK * 4;
    unsigned* Cpk       = (unsigned*)ws;
    float*    S2tab     = (float*)(ws + CP_BYTES);
    float*    nsum_part = (float*)(ws + CP_BYTES + S2_BYTES);     // 2048 floats

    logits_kernel<<<NB * NT / 128, 256, 0, stream>>>(x, labels, emb, fc_w, fc_b,
                                                     out, nsum_part, out_scalar);
    scan_kernel<<<dim3(NCHUNK, NB), 128, 0, stream>>>(trans, out, Cpk, S2tab);
    combine_kernel<<<NB, 64, 0, stream>>>(labels, out, start_t, end_t, trans,
                                          Cpk, S2tab, nsum_part, out_scalar);
}